// Round 1
// baseline (10922.663 us; speedup 1.0000x reference)
//
#include <hip/hip_runtime.h>
#include <hip/hip_bf16.h>

typedef __bf16 bf16;
typedef bf16 bf16x8 __attribute__((ext_vector_type(8)));
typedef float f32x4 __attribute__((ext_vector_type(4)));
typedef unsigned int u32;
typedef u32 u32x4 __attribute__((ext_vector_type(4)));

#define AGENT __HIP_MEMORY_SCOPE_AGENT

// ---- problem sizes ----
#define TT 512
#define BB 64
#define HH 512
#define TB (TT*BB)      // 32768 rows
#define G3 (3*HH)       // 1536 gates per dir

// ---- workspace layout (bytes) ----
#define GI_OFF   0L
#define GI_BYTES (2L*TB*G3*2)          // bf16 gi, both dirs: 201326592
#define L0_OFF   (GI_OFF + GI_BYTES)
#define L0_BYTES (1L*TB*1024*2)        // bf16 layer-0 output: 67108864
#define XB_OFF   (L0_OFF + L0_BYTES)
#define XB_BYTES (1L*TB*512*2)         // bf16 x: 33554432
#define W0_OFF   (XB_OFF + XB_BYTES)
#define W0_BYTES (3072L*512*2)         // packed w_ih L0 (f then b)
#define W1_OFF   (W0_OFF + W0_BYTES)
#define W1_BYTES (3072L*1024*2)        // packed w_ih L1
#define HB_OFF   (W1_OFF + W1_BYTES)
#define HB_BYTES (2L*2*64*256*4)       // h exchange: [phase][dir][64][256] u32 (bf16 pairs)
#define CTR_OFF  (HB_OFF + HB_BYTES)
#define WS_NEED  (CTR_OFF + 256)

// ============================ helpers ============================
__device__ __forceinline__ float sigm(float x) {
    return __builtin_amdgcn_rcpf(1.0f + __expf(-x));
}
__device__ __forceinline__ float tanh_f(float x) {
    // tanh(x) = 1 - 2/(exp(2x)+1)
    return 1.0f - 2.0f * __builtin_amdgcn_rcpf(1.0f + __expf(2.0f * x));
}

// monotonic-counter barrier among all blocks of one recurrence launch.
// All cross-WG data (hbuf) moves via cache-bypassing agent-scope atomics, so
// relaxed ordering + __syncthreads (compiler fence + vmcnt drain) suffices.
__device__ __forceinline__ void gbar(u32* c, u32 target) {
    __syncthreads();
    if (threadIdx.x == 0) {
        __hip_atomic_fetch_add(c, 1u, __ATOMIC_RELAXED, AGENT);
        while (__hip_atomic_load(c, __ATOMIC_RELAXED, AGENT) < target) {}
    }
    __syncthreads();
}

// ============================ kernels ============================
__global__ void sentinel(float* o) { o[0] = 1.0e9f; }  // ws too small marker

__global__ void cvt_f32_bf16(const float* __restrict__ s, bf16* __restrict__ d, long n) {
    long i = (long)blockIdx.x * blockDim.x + threadIdx.x;
    long st = (long)gridDim.x * blockDim.x;
    for (; i < n; i += st) d[i] = (bf16)s[i];
}

// C[m, n] = sum_k A[m,k] * Bw[n,k]; A row-major [32768,K] bf16, Bw [3072,K] bf16.
// Output written as bf16 into gi[dir][m][col], dir = n>=1536.
// 128x128 tile, KB=64, 4 waves each computing 64x64 via 4x4 MFMA 16x16x32.
__global__ __launch_bounds__(256, 2)
void gemm_gi(const bf16* __restrict__ A, const bf16* __restrict__ Bw,
             bf16* __restrict__ gi, int K)
{
    __shared__ bf16 aS[128*72];   // rows padded 64->72 bf16 (bank-conflict free b128 reads)
    __shared__ bf16 bS[128*72];
    const int tid = threadIdx.x;
    const int mt = blockIdx.x & 255;     // 256 m-tiles
    const int nt = blockIdx.x >> 8;      // 24 n-tiles
    const long m0 = (long)mt * 128;
    const int n0 = nt * 128;
    const int wave = tid >> 6, lane = tid & 63;
    const int q = lane >> 4, lr = lane & 15;
    const int wm = wave & 1, wn = wave >> 1;
    f32x4 acc[4][4] = {};

    for (int kb = 0; kb < K; kb += 64) {
        __syncthreads();
        #pragma unroll
        for (int p = 0; p < 4; ++p) {
            int idx = tid + p * 256;         // 0..1023 = 128 rows x 8 chunks
            int row = idx >> 3, qd = idx & 7;
            *(uint4*)(aS + row*72 + qd*8) = *(const uint4*)(A + (m0+row)*K + kb + qd*8);
            *(uint4*)(bS + row*72 + qd*8) = *(const uint4*)(Bw + (long)(n0+row)*K + kb + qd*8);
        }
        __syncthreads();
        #pragma unroll
        for (int kk = 0; kk < 2; ++kk) {
            bf16x8 af[4], bfr[4];
            #pragma unroll
            for (int sm = 0; sm < 4; ++sm)
                af[sm] = *(const bf16x8*)(aS + (wm*64 + sm*16 + lr)*72 + kk*32 + q*8);
            #pragma unroll
            for (int sn = 0; sn < 4; ++sn)
                bfr[sn] = *(const bf16x8*)(bS + (wn*64 + sn*16 + lr)*72 + kk*32 + q*8);
            #pragma unroll
            for (int sm = 0; sm < 4; ++sm)
                #pragma unroll
                for (int sn = 0; sn < 4; ++sn)
                    acc[sm][sn] = __builtin_amdgcn_mfma_f32_16x16x32_bf16(
                        af[sm], bfr[sn], acc[sm][sn], 0, 0, 0);
        }
    }
    // epilogue: C/D layout col=lane&15, row=q*4+reg. Pack col pairs -> u32 stores.
    #pragma unroll
    for (int sm = 0; sm < 4; ++sm) {
        #pragma unroll
        for (int sn = 0; sn < 4; ++sn) {
            int n_g = n0 + wn*64 + sn*16 + lr;
            int d = (n_g >= G3) ? 1 : 0;
            int cg = n_g - d * G3;
            u32* gout = (u32*)(gi + (long)d * TB * G3);
            #pragma unroll
            for (int i = 0; i < 4; ++i) {
                long m_g = m0 + wm*64 + sm*16 + q*4 + i;
                unsigned short hs = __builtin_bit_cast(unsigned short, (bf16)acc[sm][sn][i]);
                int other = __shfl_xor((int)hs, 1, 64);
                if (!(lr & 1))
                    gout[(m_g * G3 + cg) >> 1] = (u32)hs | (((u32)(unsigned short)other) << 16);
            }
        }
    }
}

// Persistent recurrence: 64 blocks (2 dirs x 32 h-slices of 16 cols), 256 thr.
// Each WG holds its W_hh slab [3 gates][16 cols][512] bf16 in LDS; per step it
// reads full h[64,512] bf16 via agent-scope (cache-bypassing) loads, 48 MFMAs
// per wave, fused GRU gates in fp32, publishes its h-slice, spin barrier.
__global__ __launch_bounds__(256, 1)
void gru_rec(const bf16* __restrict__ gi,
             const float* __restrict__ whh_f, const float* __restrict__ whh_b,
             const float* __restrict__ bih_f, const float* __restrict__ bhh_f,
             const float* __restrict__ bih_b, const float* __restrict__ bhh_b,
             const float* __restrict__ h0,
             u32* hbuf, u32* ctr,
             void* out, float* hn_out, int layer, int out_f32)
{
    __shared__ bf16 wS[48*520];   // rows padded 512->520 (2-way-free b128 reads)
    const int tid = threadIdx.x;
    const int dir = blockIdx.x & 1;
    const int slice = blockIdx.x >> 1;       // 0..31
    const int wave = tid >> 6, lane = tid & 63;
    const int q = lane >> 4, lr = lane & 15;

    const float* whh = dir ? whh_b : whh_f;
    const float* bih = dir ? bih_b : bih_f;
    const float* bhh = dir ? bhh_b : bhh_f;

    // stage W_hh slice -> LDS bf16 (one-time)
    for (int idx = tid; idx < 48*512; idx += 256) {
        int row = idx >> 9;                  // g*16 + c
        int k = idx & 511;
        int g = row >> 4, c = row & 15;
        wS[row*520 + k] = (bf16)whh[(g*HH + slice*16 + c)*HH + k];
    }

    const int col = slice*16 + lr;           // this lane's h column
    const float bi0 = bih[col], bi1 = bih[HH+col], bi2 = bih[2*HH+col];
    const float bh0 = bhh[col], bh1 = bhh[HH+col], bh2 = bhh[2*HH+col];

    const int mrow = wave*16 + q*4;          // batch base for acc regs i=0..3
    float hprev[4];
    #pragma unroll
    for (int i = 0; i < 4; ++i)
        hprev[i] = h0[((2*layer + dir)*BB + mrow + i)*HH + col];

    auto hb_base = [&](int ph) { return hbuf + (((ph << 1) | dir) * 64) * 256; };

    // publish initial h (phase 0): pack (even,odd) col pair via shfl
    {
        u32* hb = hb_base(0);
        #pragma unroll
        for (int i = 0; i < 4; ++i) {
            unsigned short hs = __builtin_bit_cast(unsigned short, (bf16)hprev[i]);
            int other = __shfl_xor((int)hs, 1, 64);
            if (!(lr & 1)) {
                u32 u = (u32)hs | (((u32)(unsigned short)other) << 16);
                __hip_atomic_store(hb + (mrow+i)*256 + (col >> 1), u, __ATOMIC_RELAXED, AGENT);
            }
        }
    }

    const bf16* gbase = gi + (long)dir * TB * G3;
    // prefetch gi for step 0
    int t = dir ? (TT-1) : 0;
    bf16 gp[3][4];
    #pragma unroll
    for (int g = 0; g < 3; ++g)
        #pragma unroll
        for (int i = 0; i < 4; ++i)
            gp[g][i] = gbase[(long)(t*BB + mrow + i)*G3 + g*HH + col];

    gbar(ctr, 64);

    const int arow_off = (wave*16 + lr) * 256;   // A-frag row: m = wave*16 + (lane&15)

    for (int s = 0; s < TT; ++s) {
        t = dir ? (TT-1-s) : s;
        // ---- gh = h @ W_slice^T (M=64 split over 4 waves, N=48 = 3 gate tiles)
        f32x4 acc0 = {0,0,0,0}, acc1 = {0,0,0,0}, acc2 = {0,0,0,0};
        u32* hr = hb_base(s & 1) + arow_off;
        #pragma unroll
        for (int kk = 0; kk < 16; ++kk) {
            u32x4 au;
            au.x = __hip_atomic_load(hr + kk*16 + q*4 + 0, __ATOMIC_RELAXED, AGENT);
            au.y = __hip_atomic_load(hr + kk*16 + q*4 + 1, __ATOMIC_RELAXED, AGENT);
            au.z = __hip_atomic_load(hr + kk*16 + q*4 + 2, __ATOMIC_RELAXED, AGENT);
            au.w = __hip_atomic_load(hr + kk*16 + q*4 + 3, __ATOMIC_RELAXED, AGENT);
            bf16x8 av = __builtin_bit_cast(bf16x8, au);
            bf16x8 b0 = *(const bf16x8*)(wS + ( 0 + lr)*520 + kk*32 + q*8);
            bf16x8 b1 = *(const bf16x8*)(wS + (16 + lr)*520 + kk*32 + q*8);
            bf16x8 b2 = *(const bf16x8*)(wS + (32 + lr)*520 + kk*32 + q*8);
            acc0 = __builtin_amdgcn_mfma_f32_16x16x32_bf16(av, b0, acc0, 0,0,0);
            acc1 = __builtin_amdgcn_mfma_f32_16x16x32_bf16(av, b1, acc1, 0,0,0);
            acc2 = __builtin_amdgcn_mfma_f32_16x16x32_bf16(av, b2, acc2, 0,0,0);
        }
        // ---- fused gates (fp32)
        float hnew[4];
        #pragma unroll
        for (int i = 0; i < 4; ++i) {
            float r = sigm((float)gp[0][i] + bi0 + acc0[i] + bh0);
            float z = sigm((float)gp[1][i] + bi1 + acc1[i] + bh1);
            float n = tanh_f((float)gp[2][i] + bi2 + r * (acc2[i] + bh2));
            float h = (1.0f - z) * n + z * hprev[i];
            hprev[i] = h;
            hnew[i] = h;
        }
        // ---- publish h_new to other phase
        {
            u32* hb = hb_base((s+1) & 1);
            #pragma unroll
            for (int i = 0; i < 4; ++i) {
                unsigned short hs = __builtin_bit_cast(unsigned short, (bf16)hnew[i]);
                int other = __shfl_xor((int)hs, 1, 64);
                if (!(lr & 1)) {
                    u32 u = (u32)hs | (((u32)(unsigned short)other) << 16);
                    __hip_atomic_store(hb + (mrow+i)*256 + (col >> 1), u, __ATOMIC_RELAXED, AGENT);
                }
            }
        }
        // ---- write y[t] (layer output)
        if (out_f32) {
            float* yo = (float*)out;
            #pragma unroll
            for (int i = 0; i < 4; ++i)
                yo[(long)(t*BB + mrow + i)*1024 + dir*HH + col] = hnew[i];
        } else {
            bf16* yo = (bf16*)out;
            #pragma unroll
            for (int i = 0; i < 4; ++i)
                yo[(long)(t*BB + mrow + i)*1024 + dir*HH + col] = (bf16)hnew[i];
        }
        if (s == TT-1) {
            #pragma unroll
            for (int i = 0; i < 4; ++i)
                hn_out[((2*layer + dir)*BB + mrow + i)*HH + col] = hnew[i];
            break;   // no barrier after final step
        }
        // ---- prefetch next gi (hides HBM latency under the barrier spin)
        int tn = dir ? (TT-2-s) : (s+1);
        #pragma unroll
        for (int g = 0; g < 3; ++g)
            #pragma unroll
            for (int i = 0; i < 4; ++i)
                gp[g][i] = gbase[(long)(tn*BB + mrow + i)*G3 + g*HH + col];
        gbar(ctr, 64u * (s + 2));
    }
}

// ============================ launch ============================
extern "C" void kernel_launch(void* const* d_in, const int* in_sizes, int n_in,
                              void* d_out, int out_size, void* d_ws, size_t ws_size,
                              hipStream_t stream)
{
    const float* x     = (const float*)d_in[0];
    const float* h0    = (const float*)d_in[1];
    const float* wih0f = (const float*)d_in[2];
    const float* whh0f = (const float*)d_in[3];
    const float* bih0f = (const float*)d_in[4];
    const float* bhh0f = (const float*)d_in[5];
    const float* wih0b = (const float*)d_in[6];
    const float* whh0b = (const float*)d_in[7];
    const float* bih0b = (const float*)d_in[8];
    const float* bhh0b = (const float*)d_in[9];
    const float* wih1f = (const float*)d_in[10];
    const float* whh1f = (const float*)d_in[11];
    const float* bih1f = (const float*)d_in[12];
    const float* bhh1f = (const float*)d_in[13];
    const float* wih1b = (const float*)d_in[14];
    const float* whh1b = (const float*)d_in[15];
    const float* bih1b = (const float*)d_in[16];
    const float* bhh1b = (const float*)d_in[17];

    if (ws_size < (size_t)WS_NEED) {
        sentinel<<<1, 1, 0, stream>>>((float*)d_out);
        return;
    }
    char* ws = (char*)d_ws;
    bf16* gi    = (bf16*)(ws + GI_OFF);
    bf16* l0out = (bf16*)(ws + L0_OFF);
    bf16* xb    = (bf16*)(ws + XB_OFF);
    bf16* w0    = (bf16*)(ws + W0_OFF);
    bf16* w1    = (bf16*)(ws + W1_OFF);
    u32*  hbuf  = (u32*)(ws + HB_OFF);
    u32*  ctr   = (u32*)(ws + CTR_OFF);
    float* hn   = (float*)d_out + (long)TB * 1024;

    hipMemsetAsync(ctr, 0, 256, stream);   // barrier counters (ws is re-poisoned each call)

    // bf16 packing
    cvt_f32_bf16<<<2048, 256, 0, stream>>>(x, xb, (long)TB * 512);
    cvt_f32_bf16<<<256, 256, 0, stream>>>(wih0f, w0,             (long)G3 * 512);
    cvt_f32_bf16<<<256, 256, 0, stream>>>(wih0b, w0 + G3*512L,   (long)G3 * 512);
    cvt_f32_bf16<<<256, 256, 0, stream>>>(wih1f, w1,             (long)G3 * 1024);
    cvt_f32_bf16<<<256, 256, 0, stream>>>(wih1b, w1 + G3*1024L,  (long)G3 * 1024);

    // layer 0
    gemm_gi<<<dim3(256 * 24), 256, 0, stream>>>(xb, w0, gi, 512);
    gru_rec<<<64, 256, 0, stream>>>(gi, whh0f, whh0b, bih0f, bhh0f, bih0b, bhh0b,
                                    h0, hbuf, ctr, (void*)l0out, hn, 0, 0);
    // layer 1
    gemm_gi<<<dim3(256 * 24), 256, 0, stream>>>(l0out, w1, gi, 1024);
    gru_rec<<<64, 256, 0, stream>>>(gi, whh1f, whh1b, bih1f, bhh1f, bih1b, bhh1b,
                                    h0, hbuf, ctr + 16, d_out, hn, 1, 1);
}

// Round 2
// 5439.521 us; speedup vs baseline: 2.0080x; 2.0080x over previous
//
#include <hip/hip_runtime.h>
#include <hip/hip_bf16.h>

typedef __bf16 bf16;
typedef bf16 bf16x8 __attribute__((ext_vector_type(8)));
typedef float f32x4 __attribute__((ext_vector_type(4)));
typedef unsigned int u32;
typedef u32 u32x4 __attribute__((ext_vector_type(4)));

#define AGENT __HIP_MEMORY_SCOPE_AGENT

// ---- problem sizes ----
#define TT 512
#define BB 64
#define HH 512
#define TB (TT*BB)      // 32768 rows
#define G3 (3*HH)       // 1536 gates per dir

// ---- workspace layout (bytes) ----
#define GI_OFF   0L
#define GI_BYTES (2L*TB*G3*2)          // bf16 gi, both dirs
#define L0_OFF   (GI_OFF + GI_BYTES)
#define L0_BYTES (1L*TB*1024*2)        // bf16 layer-0 output
#define XB_OFF   (L0_OFF + L0_BYTES)
#define XB_BYTES (1L*TB*512*2)         // bf16 x
#define W0_OFF   (XB_OFF + XB_BYTES)
#define W0_BYTES (3072L*512*2)         // packed w_ih L0 (f then b)
#define W1_OFF   (W0_OFF + W0_BYTES)
#define W1_BYTES (3072L*1024*2)        // packed w_ih L1
#define HB_OFF   (W1_OFF + W1_BYTES)
#define HB_BYTES (2L*2*64*256*4)       // h exchange: [phase][dir][64][256] u32 (bf16 pairs)
#define FL_OFF   (HB_OFF + HB_BYTES)
#define FL_BYTES 1024                  // flags[dir][wave][slice] u32
#define WS_NEED  (FL_OFF + FL_BYTES)

// ============================ helpers ============================
__device__ __forceinline__ float sigm(float x) {
    return __builtin_amdgcn_rcpf(1.0f + __expf(-x));
}
__device__ __forceinline__ float tanh_f(float x) {
    return 1.0f - 2.0f * __builtin_amdgcn_rcpf(1.0f + __expf(2.0f * x));
}

// ============================ kernels ============================
__global__ void sentinel(float* o) { o[0] = 1.0e9f; }  // ws too small marker

__global__ void cvt_f32_bf16(const float* __restrict__ s, bf16* __restrict__ d, long n) {
    long i = (long)blockIdx.x * blockDim.x + threadIdx.x;
    long st = (long)gridDim.x * blockDim.x;
    for (; i < n; i += st) d[i] = (bf16)s[i];
}

// C[m, n] = sum_k A[m,k] * Bw[n,k]; A row-major [32768,K] bf16, Bw [3072,K] bf16.
// Output written as bf16 into gi[dir][m][col], dir = n>=1536.
__global__ __launch_bounds__(256, 2)
void gemm_gi(const bf16* __restrict__ A, const bf16* __restrict__ Bw,
             bf16* __restrict__ gi, int K)
{
    __shared__ bf16 aS[128*72];
    __shared__ bf16 bS[128*72];
    const int tid = threadIdx.x;
    const int mt = blockIdx.x & 255;
    const int nt = blockIdx.x >> 8;
    const long m0 = (long)mt * 128;
    const int n0 = nt * 128;
    const int wave = tid >> 6, lane = tid & 63;
    const int q = lane >> 4, lr = lane & 15;
    const int wm = wave & 1, wn = wave >> 1;
    f32x4 acc[4][4] = {};

    for (int kb = 0; kb < K; kb += 64) {
        __syncthreads();
        #pragma unroll
        for (int p = 0; p < 4; ++p) {
            int idx = tid + p * 256;
            int row = idx >> 3, qd = idx & 7;
            *(uint4*)(aS + row*72 + qd*8) = *(const uint4*)(A + (m0+row)*K + kb + qd*8);
            *(uint4*)(bS + row*72 + qd*8) = *(const uint4*)(Bw + (long)(n0+row)*K + kb + qd*8);
        }
        __syncthreads();
        #pragma unroll
        for (int kk = 0; kk < 2; ++kk) {
            bf16x8 af[4], bfr[4];
            #pragma unroll
            for (int sm = 0; sm < 4; ++sm)
                af[sm] = *(const bf16x8*)(aS + (wm*64 + sm*16 + lr)*72 + kk*32 + q*8);
            #pragma unroll
            for (int sn = 0; sn < 4; ++sn)
                bfr[sn] = *(const bf16x8*)(bS + (wn*64 + sn*16 + lr)*72 + kk*32 + q*8);
            #pragma unroll
            for (int sm = 0; sm < 4; ++sm)
                #pragma unroll
                for (int sn = 0; sn < 4; ++sn)
                    acc[sm][sn] = __builtin_amdgcn_mfma_f32_16x16x32_bf16(
                        af[sm], bfr[sn], acc[sm][sn], 0, 0, 0);
        }
    }
    #pragma unroll
    for (int sm = 0; sm < 4; ++sm) {
        #pragma unroll
        for (int sn = 0; sn < 4; ++sn) {
            int n_g = n0 + wn*64 + sn*16 + lr;
            int d = (n_g >= G3) ? 1 : 0;
            int cg = n_g - d * G3;
            u32* gout = (u32*)(gi + (long)d * TB * G3);
            #pragma unroll
            for (int i = 0; i < 4; ++i) {
                long m_g = m0 + wm*64 + sm*16 + q*4 + i;
                unsigned short hs = __builtin_bit_cast(unsigned short, (bf16)acc[sm][sn][i]);
                int other = __shfl_xor((int)hs, 1, 64);
                if (!(lr & 1))
                    gout[(m_g * G3 + cg) >> 1] = (u32)hs | (((u32)(unsigned short)other) << 16);
            }
        }
    }
}

// Persistent recurrence: 64 blocks (2 dirs x 32 h-slices of 16 cols), 256 thr.
// Per-(dir,wave,slice) monotonic FLAG words replace the round-1 counter
// barrier (no serialized RMW chain; dirs fully decoupled; waves slip freely).
// Wave w only consumes h rows [16w,16w+16), which only writer-wave w of each
// slice publishes -> wave w polls just the 32 flags of its peer waves.
__global__ __launch_bounds__(256, 1)
void gru_rec(const bf16* __restrict__ gi,
             const float* __restrict__ whh_f, const float* __restrict__ whh_b,
             const float* __restrict__ bih_f, const float* __restrict__ bhh_f,
             const float* __restrict__ bih_b, const float* __restrict__ bhh_b,
             const float* __restrict__ h0,
             u32* hbuf, u32* flags,
             void* out, float* hn_out, int layer, int out_f32, u32 epoch)
{
    __shared__ bf16 wS[48*512];   // XOR-swizzled: chunk c stored at c^(row&7)
    const int tid = threadIdx.x;
    const int dir = blockIdx.x & 1;
    const int slice = blockIdx.x >> 1;       // 0..31
    const int wave = tid >> 6, lane = tid & 63;
    const int q = lane >> 4, lr = lane & 15;

    const float* whh = dir ? whh_b : whh_f;
    const float* bih = dir ? bih_b : bih_f;
    const float* bhh = dir ? bhh_b : bhh_f;

    // stage W_hh slice -> LDS bf16, 16B chunks, XOR bank swizzle
    for (int idx = tid; idx < 48*64; idx += 256) {
        int row = idx >> 6, c = idx & 63;
        int g = row >> 4, cc = row & 15;
        const float* src = whh + (size_t)(g*HH + slice*16 + cc)*HH + c*8;
        bf16x8 v;
        #pragma unroll
        for (int j = 0; j < 8; ++j) v[j] = (bf16)src[j];
        *(bf16x8*)(wS + row*512 + ((c ^ (row & 7)) << 3)) = v;
    }
    __syncthreads();

    const int col = slice*16 + lr;
    const float bi0 = bih[col], bi1 = bih[HH+col], bi2 = bih[2*HH+col];
    const float bh0 = bhh[col], bh1 = bhh[HH+col], bh2 = bhh[2*HH+col];
    const int mrow = wave*16 + q*4;

    u32* const myfl = flags + (dir*4 + wave)*32;   // peer-wave flags, 32 slices

    float hprev[4];
    #pragma unroll
    for (int i = 0; i < 4; ++i)
        hprev[i] = h0[((2*layer + dir)*BB + mrow + i)*HH + col];

    auto publish = [&](int ph, const float* hv) {
        u32* hb = hbuf + (((ph << 1) | dir) * 64) * 256;
        #pragma unroll
        for (int i = 0; i < 4; ++i) {
            unsigned short hs = __builtin_bit_cast(unsigned short, (bf16)hv[i]);
            int other = __shfl_xor((int)hs, 1, 64);
            if (!(lr & 1)) {
                u32 u = (u32)hs | (((u32)(unsigned short)other) << 16);
                __hip_atomic_store(hb + (mrow + i)*256 + (col >> 1), u,
                                   __ATOMIC_RELAXED, AGENT);
            }
        }
    };

    // initial h publish (phase 0) + flag
    publish(0, hprev);
    asm volatile("s_waitcnt vmcnt(0)" ::: "memory");
    if (lane == 0)
        __hip_atomic_store(myfl + slice, epoch + 1, __ATOMIC_RELAXED, AGENT);

    const bf16* gbase = gi + (long)dir * TB * G3;
    bf16 gp[3][4];
    {
        int t0 = dir ? (TT-1) : 0;
        #pragma unroll
        for (int g = 0; g < 3; ++g)
            #pragma unroll
            for (int i = 0; i < 4; ++i)
                gp[g][i] = gbase[(long)(t0*BB + mrow + i)*G3 + g*HH + col];
    }

    const int fl_lane = lane & 31;
    const int sw = lr & 7;

    for (int s = 0; s < TT; ++s) {
        const int t = dir ? (TT-1-s) : s;
        // ---- wait: phase (s&1) rows [16*wave,16*wave+16) ready from all slices
        const u32 tgt = epoch + 1 + (u32)s;
        for (;;) {
            u32 v = __hip_atomic_load(myfl + fl_lane, __ATOMIC_RELAXED, AGENT);
            if (__all((int)(v >= tgt))) break;
        }
        // ---- bulk h load: 16x dwordx4, L1/L2-bypassing (MALL-coherent)
        const u32* hr = hbuf + ((((s & 1) << 1) | dir)*64 + wave*16 + lr)*256 + q*4;
        u32x4 a0,a1,a2,a3,a4,a5,a6,a7,a8,a9,a10,a11,a12,a13,a14,a15;
        asm volatile(
            "global_load_dwordx4 %0, %16, off sc0 sc1\n\t"
            "global_load_dwordx4 %1, %16, off offset:64 sc0 sc1\n\t"
            "global_load_dwordx4 %2, %16, off offset:128 sc0 sc1\n\t"
            "global_load_dwordx4 %3, %16, off offset:192 sc0 sc1\n\t"
            "global_load_dwordx4 %4, %16, off offset:256 sc0 sc1\n\t"
            "global_load_dwordx4 %5, %16, off offset:320 sc0 sc1\n\t"
            "global_load_dwordx4 %6, %16, off offset:384 sc0 sc1\n\t"
            "global_load_dwordx4 %7, %16, off offset:448 sc0 sc1\n\t"
            "global_load_dwordx4 %8, %16, off offset:512 sc0 sc1\n\t"
            "global_load_dwordx4 %9, %16, off offset:576 sc0 sc1\n\t"
            "global_load_dwordx4 %10, %16, off offset:640 sc0 sc1\n\t"
            "global_load_dwordx4 %11, %16, off offset:704 sc0 sc1\n\t"
            "global_load_dwordx4 %12, %16, off offset:768 sc0 sc1\n\t"
            "global_load_dwordx4 %13, %16, off offset:832 sc0 sc1\n\t"
            "global_load_dwordx4 %14, %16, off offset:896 sc0 sc1\n\t"
            "s_waitcnt vmcnt(0)"
            : "=&v"(a0),"=&v"(a1),"=&v"(a2),"=&v"(a3),
              "=&v"(a4),"=&v"(a5),"=&v"(a6),"=&v"(a7),
              "=&v"(a8),"=&v"(a9),"=&v"(a10),"=&v"(a11),
              "=&v"(a12),"=&v"(a13),"=&v"(a14),"=&v"(a15)
            : "v"(hr)
            : "memory");
        // note: %15 uses offset:960 folded below via a15 load kept in order:
        asm volatile("global_load_dwordx4 %0, %1, off offset:960 sc0 sc1\n\t"
                     "s_waitcnt vmcnt(0)"
                     : "=&v"(a15) : "v"(hr) : "memory");
        // ---- 48 MFMAs (gh = h @ W_slice^T)
        f32x4 acc0 = {0,0,0,0}, acc1 = {0,0,0,0}, acc2 = {0,0,0,0};
#define KSTEP(KK, AU) { \
            bf16x8 av = __builtin_bit_cast(bf16x8, AU); \
            int c0 = (((KK)*4 + q) ^ sw) << 3; \
            bf16x8 b0 = *(const bf16x8*)(wS + ( 0 + lr)*512 + c0); \
            bf16x8 b1 = *(const bf16x8*)(wS + (16 + lr)*512 + c0); \
            bf16x8 b2 = *(const bf16x8*)(wS + (32 + lr)*512 + c0); \
            acc0 = __builtin_amdgcn_mfma_f32_16x16x32_bf16(av, b0, acc0, 0,0,0); \
            acc1 = __builtin_amdgcn_mfma_f32_16x16x32_bf16(av, b1, acc1, 0,0,0); \
            acc2 = __builtin_amdgcn_mfma_f32_16x16x32_bf16(av, b2, acc2, 0,0,0); }
        KSTEP(0,a0)  KSTEP(1,a1)  KSTEP(2,a2)  KSTEP(3,a3)
        KSTEP(4,a4)  KSTEP(5,a5)  KSTEP(6,a6)  KSTEP(7,a7)
        KSTEP(8,a8)  KSTEP(9,a9)  KSTEP(10,a10) KSTEP(11,a11)
        KSTEP(12,a12) KSTEP(13,a13) KSTEP(14,a14) KSTEP(15,a15)
#undef KSTEP
        // ---- fused gates (fp32)
        float hnew[4];
        #pragma unroll
        for (int i = 0; i < 4; ++i) {
            float r = sigm((float)gp[0][i] + bi0 + acc0[i] + bh0);
            float z = sigm((float)gp[1][i] + bi1 + acc1[i] + bh1);
            float n = tanh_f((float)gp[2][i] + bi2 + r * (acc2[i] + bh2));
            float h = (1.0f - z) * n + z * hprev[i];
            hprev[i] = h;
            hnew[i] = h;
        }
        // ---- publish h_new + flag first (get it on the wire ASAP)
        if (s < TT-1) {
            publish((s+1) & 1, hnew);
            asm volatile("s_waitcnt vmcnt(0)" ::: "memory");
            if (lane == 0)
                __hip_atomic_store(myfl + slice, epoch + 2 + (u32)s,
                                   __ATOMIC_RELAXED, AGENT);
        }
        // ---- write y[t]
        if (out_f32) {
            float* yo = (float*)out;
            #pragma unroll
            for (int i = 0; i < 4; ++i)
                yo[(long)(t*BB + mrow + i)*1024 + dir*HH + col] = hnew[i];
        } else {
            bf16* yo = (bf16*)out;
            #pragma unroll
            for (int i = 0; i < 4; ++i)
                yo[(long)(t*BB + mrow + i)*1024 + dir*HH + col] = (bf16)hnew[i];
        }
        if (s == TT-1) {
            #pragma unroll
            for (int i = 0; i < 4; ++i)
                hn_out[((2*layer + dir)*BB + mrow + i)*HH + col] = hnew[i];
            break;
        }
        // ---- prefetch next gi (hides under the next poll)
        int tn = dir ? (TT-2-s) : (s+1);
        #pragma unroll
        for (int g = 0; g < 3; ++g)
            #pragma unroll
            for (int i = 0; i < 4; ++i)
                gp[g][i] = gbase[(long)(tn*BB + mrow + i)*G3 + g*HH + col];
    }
}

// ============================ launch ============================
extern "C" void kernel_launch(void* const* d_in, const int* in_sizes, int n_in,
                              void* d_out, int out_size, void* d_ws, size_t ws_size,
                              hipStream_t stream)
{
    const float* x     = (const float*)d_in[0];
    const float* h0    = (const float*)d_in[1];
    const float* wih0f = (const float*)d_in[2];
    const float* whh0f = (const float*)d_in[3];
    const float* bih0f = (const float*)d_in[4];
    const float* bhh0f = (const float*)d_in[5];
    const float* wih0b = (const float*)d_in[6];
    const float* whh0b = (const float*)d_in[7];
    const float* bih0b = (const float*)d_in[8];
    const float* bhh0b = (const float*)d_in[9];
    const float* wih1f = (const float*)d_in[10];
    const float* whh1f = (const float*)d_in[11];
    const float* bih1f = (const float*)d_in[12];
    const float* bhh1f = (const float*)d_in[13];
    const float* wih1b = (const float*)d_in[14];
    const float* whh1b = (const float*)d_in[15];
    const float* bih1b = (const float*)d_in[16];
    const float* bhh1b = (const float*)d_in[17];

    if (ws_size < (size_t)WS_NEED) {
        sentinel<<<1, 1, 0, stream>>>((float*)d_out);
        return;
    }
    char* ws = (char*)d_ws;
    bf16* gi    = (bf16*)(ws + GI_OFF);
    bf16* l0out = (bf16*)(ws + L0_OFF);
    bf16* xb    = (bf16*)(ws + XB_OFF);
    bf16* w0    = (bf16*)(ws + W0_OFF);
    bf16* w1    = (bf16*)(ws + W1_OFF);
    u32*  hbuf  = (u32*)(ws + HB_OFF);
    u32*  flags = (u32*)(ws + FL_OFF);
    float* hn   = (float*)d_out + (long)TB * 1024;

    hipMemsetAsync(flags, 0, FL_BYTES, stream);

    // bf16 packing
    cvt_f32_bf16<<<2048, 256, 0, stream>>>(x, xb, (long)TB * 512);
    cvt_f32_bf16<<<256, 256, 0, stream>>>(wih0f, w0,             (long)G3 * 512);
    cvt_f32_bf16<<<256, 256, 0, stream>>>(wih0b, w0 + G3*512L,   (long)G3 * 512);
    cvt_f32_bf16<<<256, 256, 0, stream>>>(wih1f, w1,             (long)G3 * 1024);
    cvt_f32_bf16<<<256, 256, 0, stream>>>(wih1b, w1 + G3*1024L,  (long)G3 * 1024);

    // layer 0
    gemm_gi<<<dim3(256 * 24), 256, 0, stream>>>(xb, w0, gi, 512);
    gru_rec<<<64, 256, 0, stream>>>(gi, whh0f, whh0b, bih0f, bhh0f, bih0b, bhh0b,
                                    h0, hbuf, flags, (void*)l0out, hn, 0, 0, 0u);
    // layer 1
    gemm_gi<<<dim3(256 * 24), 256, 0, stream>>>(l0out, w1, gi, 1024);
    gru_rec<<<64, 256, 0, stream>>>(gi, whh1f, whh1b, bih1f, bhh1f, bih1b, bhh1b,
                                    h0, hbuf, flags, d_out, hn, 1, 1, 4096u);
}